// Round 7
// baseline (574.601 us; speedup 1.0000x reference)
//
#include <hip/hip_runtime.h>
#include <hip/hip_bf16.h>
#include <stdint.h>

// Experts MoE-MLP: o = silu((x@wfc+bfc)*(x@wg+bg)) @ wp + bp   (all fp32 I/O)
// R11: R8 2-phase structure, but MFMA shape switched to 32x32x16 bf16
//      (µbench 2495 vs 2176 TF = +15% pipe rate, half the instructions).
//      Same LDS layout/staging/swizzle/ring/vmcnt; frag reads re-addressed
//      for the 32-row operand layout; epilogues use the 32x32 C/D mapping:
//      col=lane&31, row=(reg&3)+8*(reg>>2)+4*(lane>>5).
//      T1 XCD swizzle + T2 LDS swizzle + dual-half proj retained.

#define T_ 2048
#define D_ 1024
#define H_ 4096
#define NE 8

typedef unsigned short u16;
typedef __attribute__((ext_vector_type(8))) u16 u16x8;
typedef __attribute__((ext_vector_type(4))) u16 u16x4;
typedef __attribute__((ext_vector_type(8))) short bf16x8;
typedef __attribute__((ext_vector_type(16))) float f32x16;

__device__ __forceinline__ uint32_t bf16_rne(float f) {
    union { float f; uint32_t u; } v; v.f = f;
    return (v.u + 0x7FFFu + ((v.u >> 16) & 1u)) >> 16;
}

// async global->LDS, 16B per lane; LDS dest is wave-uniform base + lane*16
__device__ __forceinline__ void gload16(const void* g, void* l) {
    __builtin_amdgcn_global_load_lds((const __attribute__((address_space(1))) void*)g,
                                     (__attribute__((address_space(3))) void*)l,
                                     16, 0, 0);
}

#define SBAR() __builtin_amdgcn_s_barrier()
#define SB0()  __builtin_amdgcn_sched_barrier(0)

// ---------- prep: elementwise x -> bf16 ----------
__global__ __launch_bounds__(256) void tobf16_kernel(const float* __restrict__ in,
    u16* __restrict__ oh, int n4) {
    int i = blockIdx.x * 256 + threadIdx.x;
    if (i >= n4) return;
    float4 v = reinterpret_cast<const float4*>(in)[i];
    float c[4] = {v.x, v.y, v.z, v.w};
    u16x4 h{};
#pragma unroll
    for (int j = 0; j < 4; ++j) h[j] = (u16)bf16_rne(c[j]);
    reinterpret_cast<u16x4*>(oh)[i] = h;
}

// ---------- prep: per-expert transpose [R][C] -> [C][R] + bf16 ----------
__global__ __launch_bounds__(256) void transpose_hi_kernel(
    const float* __restrict__ in, u16* __restrict__ oh, int R, int C) {
    __shared__ float tile[64][65];
    const int z = blockIdx.z;
    const int r0 = blockIdx.x * 64, c0 = blockIdx.y * 64;
    const float* src = in + (size_t)z * R * C;
    const int tr = threadIdx.x >> 4;
    const int tc = (threadIdx.x & 15) * 4;
#pragma unroll
    for (int j = 0; j < 4; ++j) {
        const float4 v = *reinterpret_cast<const float4*>(&src[(size_t)(r0 + tr + j*16) * C + c0 + tc]);
        tile[tr + j*16][tc+0] = v.x; tile[tr + j*16][tc+1] = v.y;
        tile[tr + j*16][tc+2] = v.z; tile[tr + j*16][tc+3] = v.w;
    }
    __syncthreads();
    const int cl = threadIdx.x & 63;
    const int q  = threadIdx.x >> 6;
    u16x8 h0{}, h1{};
#pragma unroll
    for (int rr = 0; rr < 8; ++rr) h0[rr] = (u16)bf16_rne(tile[q*16 + rr][cl]);
#pragma unroll
    for (int rr = 0; rr < 8; ++rr) h1[rr] = (u16)bf16_rne(tile[q*16 + 8 + rr][cl]);
    size_t ob = ((size_t)z * C + c0 + cl) * R + r0 + q*16;
    *reinterpret_cast<u16x8*>(&oh[ob])     = h0;
    *reinterpret_cast<u16x8*>(&oh[ob + 8]) = h1;
}

// ================= shared dual-operand K-step (R11: 32x32x16) =================
// LDS unit: A 256x32 @0 | B 128x32 @8192 | G 128x32 @12288 (u16 offsets),
// ring of 4 units = 128 KiB. 8 waves 4x2, wave tile 64x64 per operand pair
// as 2x2 of 32x32 MFMA tiles, K=32 as 2 k-halves.
// Operand layout (32x32x16): row = lane&31, k = 8*(lane>>5)+j.
// Frag addr: base + (tile)*1024 + ck[kh], ck[kh] = ((kh*2 + (lane>>5)) ^
// (((lane&31)>>1)&3)) * 8  (T2 chunk swizzle, matches write side).
// Step t: phase H: read Af(4),Bf(4) + gload A(t+3) -> SB0 -> SBAR ->
//   8 h-MFMA; phase G: read Gf(4) + gload B,G(t+3) -> SB0 -> vmcnt(8) ->
//   SBAR [publish t+1] -> 8 g-MFMA.
// Hazards identical to R8 (same byte schedule, only read/MFMA shapes differ).

template<bool PF, int VM>
__device__ __forceinline__ void duo_step(int tt, u16 (*sm)[16384],
    const u16* asrc, const u16* bsrc, const u16* gsrc, size_t a16str,
    int adst0, int adst1, int bdst, int gdst,
    int aoff, int boff, int goff, int ck0, int ck1,
    f32x16 (&acch)[2][2], f32x16 (&accg)[2][2])
{
    const u16* sb = &sm[tt & 3][0];
    u16* db = &sm[(tt + 3) & 3][0];
    const size_t k0 = (size_t)(tt + 3) * 32;
    bf16x8 Af[4], Bf[4], Gf[4];    // [tile*2 + kh]
    // ---- phase H ----
#pragma unroll
    for (int mi = 0; mi < 2; ++mi) {
        Af[mi*2+0] = *(const bf16x8*)(sb + aoff + mi * 1024 + ck0);
        Af[mi*2+1] = *(const bf16x8*)(sb + aoff + mi * 1024 + ck1);
    }
#pragma unroll
    for (int ni = 0; ni < 2; ++ni) {
        Bf[ni*2+0] = *(const bf16x8*)(sb + boff + ni * 1024 + ck0);
        Bf[ni*2+1] = *(const bf16x8*)(sb + boff + ni * 1024 + ck1);
    }
    if (PF) {
        gload16(asrc + k0, db + adst0);
        gload16(asrc + k0 + a16str, db + adst1);
    }
    SB0();   // pin reads/gloads before the barrier
    SBAR();
    __builtin_amdgcn_s_setprio(1);
#pragma unroll
    for (int mi = 0; mi < 2; ++mi)
#pragma unroll
        for (int ni = 0; ni < 2; ++ni)
#pragma unroll
            for (int kh = 0; kh < 2; ++kh)
                acch[mi][ni] = __builtin_amdgcn_mfma_f32_32x32x16_bf16(
                    Af[mi*2+kh], Bf[ni*2+kh], acch[mi][ni], 0, 0, 0);
    __builtin_amdgcn_s_setprio(0);
    // ---- phase G ----
#pragma unroll
    for (int ni = 0; ni < 2; ++ni) {
        Gf[ni*2+0] = *(const bf16x8*)(sb + goff + ni * 1024 + ck0);
        Gf[ni*2+1] = *(const bf16x8*)(sb + goff + ni * 1024 + ck1);
    }
    if (PF) {
        gload16(bsrc + k0, db + bdst);
        gload16(gsrc + k0, db + gdst);
    }
    SB0();
    if (VM == 8)      asm volatile("s_waitcnt vmcnt(8)" ::: "memory");
    else if (VM == 4) asm volatile("s_waitcnt vmcnt(4)" ::: "memory");
    else if (VM == 0) asm volatile("s_waitcnt vmcnt(0)" ::: "memory");
    if (VM >= 0) SBAR();   // publish unit t+1
    __builtin_amdgcn_s_setprio(1);
#pragma unroll
    for (int mi = 0; mi < 2; ++mi)
#pragma unroll
        for (int ni = 0; ni < 2; ++ni)
#pragma unroll
            for (int kh = 0; kh < 2; ++kh)
                accg[mi][ni] = __builtin_amdgcn_mfma_f32_32x32x16_bf16(
                    Af[mi*2+kh], Gf[ni*2+kh], accg[mi][ni], 0, 0, 0);
    __builtin_amdgcn_s_setprio(0);
}

// ================= fc_gate: act = silu((x@wfc+bfc)*(x@wg+bg)) =================
__global__ __launch_bounds__(512, 2) void gemm_fc_gate(
    const u16* __restrict__ xh, const u16* __restrict__ fh, const u16* __restrict__ gh,
    const float* __restrict__ bfc, const float* __restrict__ bgt,
    u16* __restrict__ act)
{
    __shared__ __align__(16) u16 sm[4][16384];   // 128 KiB
    const int z  = blockIdx.z;
    // T1: bijective XCD swizzle (256 blocks/expert) -> 4 B/G panels per XCD L2
    const int lin = blockIdx.x + (blockIdx.y << 3);          // gridDim.x == 8
    const int swz = ((lin & 7) << 5) + (lin >> 3);
    const int m0 = (swz & 7) * 256;
    const int n0 = (swz >> 3) * 128;
    const int tid = threadIdx.x;
    const int lane = tid & 63;
    const int wid = tid >> 6;
    const int wr = wid >> 1;     // 0..3
    const int wc = wid & 1;      // 0..1

    // T2 write side: physical chunk (lane&3) of row (lane>>2) carries logical
    // chunk (lane&3) ^ ((row>>1)&3)
    const int cs = ((lane & 3) ^ ((lane >> 3) & 3)) * 8;
    const u16* asrc = xh + ((size_t)z * T_ + m0 + wid * 32 + (lane >> 2)) * D_ + cs;
    const u16* bsrc = fh + ((size_t)z * H_ + n0 + wid * 16 + (lane >> 2)) * D_ + cs;
    const u16* gsrc = gh + ((size_t)z * H_ + n0 + wid * 16 + (lane >> 2)) * D_ + cs;
    const int adst0 = wid * 1024;
    const int adst1 = adst0 + 512;
    const int bdst  = 8192 + wid * 512;
    const int gdst  = 12288 + wid * 512;

    // T2 read side (32x32 operand layout)
    const int kq = lane >> 5;
    const int cswz = ((lane & 31) >> 1) & 3;
    const int ck0 = ((0 * 2 + kq) ^ cswz) * 8;
    const int ck1 = ((1 * 2 + kq) ^ cswz) * 8;
    const int aoff = (wr * 64 + (lane & 31)) * 32;
    const int boff = 8192 + (wc * 64 + (lane & 31)) * 32;
    const int goff = boff + 4096;

    f32x16 acch[2][2], accg[2][2];
#pragma unroll
    for (int i = 0; i < 2; ++i)
#pragma unroll
        for (int j = 0; j < 2; ++j) {
            acch[i][j] = (f32x16)(0.f);
            accg[i][j] = (f32x16)(0.f);
        }

    // prologue: stage units 0,1,2 (A,A,B,G per unit)
#pragma unroll
    for (int u = 0; u < 3; ++u) {
        u16* db = &sm[u][0];
        gload16(asrc + u * 32, db + adst0);
        gload16(asrc + u * 32 + (size_t)16 * D_, db + adst1);
        gload16(bsrc + u * 32, db + bdst);
        gload16(gsrc + u * 32, db + gdst);
    }
    asm volatile("s_waitcnt vmcnt(8)" ::: "memory");   // unit 0 landed (this wave)
    SBAR();                                            // unit 0 published

    const size_t a16 = (size_t)16 * D_;
#pragma unroll 2
    for (int t = 0; t < 28; ++t)
        duo_step<true, 8>(t, sm, asrc, bsrc, gsrc, a16, adst0, adst1, bdst, gdst,
                          aoff, boff, goff, ck0, ck1, acch, accg);
    duo_step<true,  8>(28, sm, asrc, bsrc, gsrc, a16, adst0, adst1, bdst, gdst,
                       aoff, boff, goff, ck0, ck1, acch, accg);
    duo_step<false, 4>(29, sm, asrc, bsrc, gsrc, a16, adst0, adst1, bdst, gdst,
                       aoff, boff, goff, ck0, ck1, acch, accg);
    duo_step<false, 0>(30, sm, asrc, bsrc, gsrc, a16, adst0, adst1, bdst, gdst,
                       aoff, boff, goff, ck0, ck1, acch, accg);
    duo_step<false, -1>(31, sm, asrc, bsrc, gsrc, a16, adst0, adst1, bdst, gdst,
                       aoff, boff, goff, ck0, ck1, acch, accg);

    // epilogue: silu(h*g) -> bf16; 32x32 C/D: col=lane&31,
    // row=(r&3)+8*(r>>2)+4*(lane>>5)
#pragma unroll
    for (int mi = 0; mi < 2; ++mi) {
#pragma unroll
        for (int ni = 0; ni < 2; ++ni) {
            const int col = n0 + wc * 64 + ni * 32 + (lane & 31);
            const float bh = bfc[(size_t)z * H_ + col];
            const float bg = bgt[(size_t)z * H_ + col];
#pragma unroll
            for (int r = 0; r < 16; ++r) {
                const int rowl = (r & 3) + 8 * (r >> 2) + 4 * (lane >> 5);
                const int row = m0 + wr * 64 + mi * 32 + rowl;
                float h = acch[mi][ni][r] + bh;
                float g = accg[mi][ni][r] + bg;
                float zz = h * g;
                float s = zz * __builtin_amdgcn_rcpf(1.0f + __expf(-zz));
                act[((size_t)z * T_ + row) * H_ + col] = (u16)bf16_rne(s);
            }
        }
    }
}

// ================= proj: out = act @ wp + bp =================
// Same dual-operand structure: BN=256 as two 128-col halves of wp (B and G).
__global__ __launch_bounds__(512, 2) void gemm_proj(
    const u16* __restrict__ act, const u16* __restrict__ ph,
    const float* __restrict__ bp, float* __restrict__ out)
{
    __shared__ __align__(16) u16 sm[4][16384];   // 128 KiB
    const int z  = blockIdx.z;
    // 32 tiles/expert: bm = lin&7 (one A-panel per XCD, 2 MB L2-resident), bn = lin>>3
    const int lin = blockIdx.x;                  // gridDim.x == 32
    const int m0 = (lin & 7) * 256;
    const int n0 = (lin >> 3) * 256;
    const int tid = threadIdx.x;
    const int lane = tid & 63;
    const int wid = tid >> 6;
    const int wr = wid >> 1;
    const int wc = wid & 1;

    const int cs = ((lane & 3) ^ ((lane >> 3) & 3)) * 8;
    const u16* asrc = act + ((size_t)z * T_ + m0 + wid * 32 + (lane >> 2)) * H_ + cs;
    const u16* bsrc = ph  + ((size_t)z * D_ + n0 + wid * 16 + (lane >> 2)) * H_ + cs;
    const u16* gsrc = ph  + ((size_t)z * D_ + n0 + 128 + wid * 16 + (lane >> 2)) * H_ + cs;
    const int adst0 = wid * 1024;
    const int adst1 = adst0 + 512;
    const int bdst  = 8192 + wid * 512;
    const int gdst  = 12288 + wid * 512;

    const int kq = lane >> 5;
    const int cswz = ((lane & 31) >> 1) & 3;
    const int ck0 = ((0 * 2 + kq) ^ cswz) * 8;
    const int ck1 = ((1 * 2 + kq) ^ cswz) * 8;
    const int aoff = (wr * 64 + (lane & 31)) * 32;
    const int boff = 8192 + (wc * 64 + (lane & 31)) * 32;
    const int goff = boff + 4096;

    f32x16 acch[2][2], accg[2][2];
#pragma unroll
    for (int i = 0; i < 2; ++i)
#pragma unroll
        for (int j = 0; j < 2; ++j) {
            acch[i][j] = (f32x16)(0.f);
            accg[i][j] = (f32x16)(0.f);
        }

    // prologue: stage units 0,1,2
#pragma unroll
    for (int u = 0; u < 3; ++u) {
        u16* db = &sm[u][0];
        gload16(asrc + u * 32, db + adst0);
        gload16(asrc + u * 32 + (size_t)16 * H_, db + adst1);
        gload16(bsrc + u * 32, db + bdst);
        gload16(gsrc + u * 32, db + gdst);
    }
    asm volatile("s_waitcnt vmcnt(8)" ::: "memory");
    SBAR();

    const size_t a16 = (size_t)16 * H_;
#pragma unroll 2
    for (int t = 0; t < 124; ++t)
        duo_step<true, 8>(t, sm, asrc, bsrc, gsrc, a16, adst0, adst1, bdst, gdst,
                          aoff, boff, goff, ck0, ck1, acch, accg);
    duo_step<true,  8>(124, sm, asrc, bsrc, gsrc, a16, adst0, adst1, bdst, gdst,
                       aoff, boff, goff, ck0, ck1, acch, accg);
    duo_step<false, 4>(125, sm, asrc, bsrc, gsrc, a16, adst0, adst1, bdst, gdst,
                       aoff, boff, goff, ck0, ck1, acch, accg);
    duo_step<false, 0>(126, sm, asrc, bsrc, gsrc, a16, adst0, adst1, bdst, gdst,
                       aoff, boff, goff, ck0, ck1, acch, accg);
    duo_step<false, -1>(127, sm, asrc, bsrc, gsrc, a16, adst0, adst1, bdst, gdst,
                       aoff, boff, goff, ck0, ck1, acch, accg);

    // epilogue: two fp32 column-halves + bias (32x32 C/D mapping)
#pragma unroll
    for (int mi = 0; mi < 2; ++mi) {
#pragma unroll
        for (int ni = 0; ni < 2; ++ni) {
            const int colh = n0 + wc * 64 + ni * 32 + (lane & 31);
            const int colg = colh + 128;
            const float bvh = bp[(size_t)z * D_ + colh];
            const float bvg = bp[(size_t)z * D_ + colg];
#pragma unroll
            for (int r = 0; r < 16; ++r) {
                const int rowl = (r & 3) + 8 * (r >> 2) + 4 * (lane >> 5);
                const int row = m0 + wr * 64 + mi * 32 + rowl;
                out[((size_t)z * T_ + row) * D_ + colh] = acch[mi][ni][r] + bvh;
                out[((size_t)z * T_ + row) * D_ + colg] = accg[mi][ni][r] + bvg;
            }
        }
    }
}

extern "C" void kernel_launch(void* const* d_in, const int* in_sizes, int n_in,
                              void* d_out, int out_size, void* d_ws, size_t ws_size,
                              hipStream_t stream) {
    const float* x   = (const float*)d_in[0];
    const float* wfc = (const float*)d_in[1];
    const float* bfc = (const float*)d_in[2];
    const float* wg  = (const float*)d_in[3];
    const float* bg  = (const float*)d_in[4];
    const float* wp  = (const float*)d_in[5];
    const float* bp  = (const float*)d_in[6];
    float* out = (float*)d_out;

    // per-expert ws: xh + fh/gh/ph (transposed bf16) + act(bf16) = 44 MB
    const size_t per_e = ((size_t)T_*D_ + 3*(size_t)D_*H_ + (size_t)T_*H_) * 2;
    int EB = (int)(ws_size / per_e);
    if (EB < 1) EB = 1;
    if (EB > NE) EB = NE;

    for (int e0 = 0; e0 < NE; e0 += EB) {
        const int eb = (NE - e0 < EB) ? (NE - e0) : EB;
        char* p = (char*)d_ws;
        u16* xh = (u16*)p; p += (size_t)eb*T_*D_*2;
        u16* fh = (u16*)p; p += (size_t)eb*D_*H_*2;
        u16* gh = (u16*)p; p += (size_t)eb*D_*H_*2;
        u16* ph = (u16*)p; p += (size_t)eb*H_*D_*2;
        u16* act = (u16*)p;

        const int n4 = eb * T_ * D_ / 4;
        tobf16_kernel<<<dim3((n4 + 255) / 256), 256, 0, stream>>>(
            x + (size_t)e0*T_*D_, xh, n4);
        transpose_hi_kernel<<<dim3(D_/64, H_/64, eb), 256, 0, stream>>>(
            wfc + (size_t)e0*D_*H_, fh, D_, H_);
        transpose_hi_kernel<<<dim3(D_/64, H_/64, eb), 256, 0, stream>>>(
            wg + (size_t)e0*D_*H_, gh, D_, H_);
        transpose_hi_kernel<<<dim3(H_/64, D_/64, eb), 256, 0, stream>>>(
            wp + (size_t)e0*H_*D_, ph, H_, D_);
        gemm_fc_gate<<<dim3(8, 32, eb), 512, 0, stream>>>(
            xh, fh, gh, bfc + (size_t)e0*H_, bg + (size_t)e0*H_, act);
        gemm_proj<<<dim3(32, 1, eb), 512, 0, stream>>>(
            act, ph, bp + (size_t)e0*D_, out + (size_t)e0*T_*D_);
    }
}

// Round 8
// 553.456 us; speedup vs baseline: 1.0382x; 1.0382x over previous
//
#include <hip/hip_runtime.h>
#include <hip/hip_bf16.h>
#include <stdint.h>

// Experts MoE-MLP: o = silu((x@wfc+bfc)*(x@wg+bg)) @ wp + bp   (all fp32 I/O)
// R12: revert to R8 (measured best, 556.6 us). m201-equivalent structure:
//      ring-4 x K32 LDS units (== m201 2dbuf x K64), counted vmcnt(8),
//      pre-barrier operand reads, 2x16-MFMA phases, T1 XCD swizzle,
//      T2 chunk-XOR LDS swizzle (0 conflicts), dual-half proj.
//      32x32 MFMA shape rejected (R11: +4 cyc/read bank-conflict tax).

#define T_ 2048
#define D_ 1024
#define H_ 4096
#define NE 8

typedef unsigned short u16;
typedef __attribute__((ext_vector_type(8))) u16 u16x8;
typedef __attribute__((ext_vector_type(4))) u16 u16x4;
typedef __attribute__((ext_vector_type(8))) short bf16x8;
typedef __attribute__((ext_vector_type(4))) float f32x4;

__device__ __forceinline__ uint32_t bf16_rne(float f) {
    union { float f; uint32_t u; } v; v.f = f;
    return (v.u + 0x7FFFu + ((v.u >> 16) & 1u)) >> 16;
}

// async global->LDS, 16B per lane; LDS dest is wave-uniform base + lane*16
__device__ __forceinline__ void gload16(const void* g, void* l) {
    __builtin_amdgcn_global_load_lds((const __attribute__((address_space(1))) void*)g,
                                     (__attribute__((address_space(3))) void*)l,
                                     16, 0, 0);
}

#define SBAR() __builtin_amdgcn_s_barrier()
#define SB0()  __builtin_amdgcn_sched_barrier(0)

// ---------- prep: elementwise x -> bf16 ----------
__global__ __launch_bounds__(256) void tobf16_kernel(const float* __restrict__ in,
    u16* __restrict__ oh, int n4) {
    int i = blockIdx.x * 256 + threadIdx.x;
    if (i >= n4) return;
    float4 v = reinterpret_cast<const float4*>(in)[i];
    float c[4] = {v.x, v.y, v.z, v.w};
    u16x4 h{};
#pragma unroll
    for (int j = 0; j < 4; ++j) h[j] = (u16)bf16_rne(c[j]);
    reinterpret_cast<u16x4*>(oh)[i] = h;
}

// ---------- prep: per-expert transpose [R][C] -> [C][R] + bf16 ----------
__global__ __launch_bounds__(256) void transpose_hi_kernel(
    const float* __restrict__ in, u16* __restrict__ oh, int R, int C) {
    __shared__ float tile[64][65];
    const int z = blockIdx.z;
    const int r0 = blockIdx.x * 64, c0 = blockIdx.y * 64;
    const float* src = in + (size_t)z * R * C;
    const int tr = threadIdx.x >> 4;
    const int tc = (threadIdx.x & 15) * 4;
#pragma unroll
    for (int j = 0; j < 4; ++j) {
        const float4 v = *reinterpret_cast<const float4*>(&src[(size_t)(r0 + tr + j*16) * C + c0 + tc]);
        tile[tr + j*16][tc+0] = v.x; tile[tr + j*16][tc+1] = v.y;
        tile[tr + j*16][tc+2] = v.z; tile[tr + j*16][tc+3] = v.w;
    }
    __syncthreads();
    const int cl = threadIdx.x & 63;
    const int q  = threadIdx.x >> 6;
    u16x8 h0{}, h1{};
#pragma unroll
    for (int rr = 0; rr < 8; ++rr) h0[rr] = (u16)bf16_rne(tile[q*16 + rr][cl]);
#pragma unroll
    for (int rr = 0; rr < 8; ++rr) h1[rr] = (u16)bf16_rne(tile[q*16 + 8 + rr][cl]);
    size_t ob = ((size_t)z * C + c0 + cl) * R + r0 + q*16;
    *reinterpret_cast<u16x8*>(&oh[ob])     = h0;
    *reinterpret_cast<u16x8*>(&oh[ob + 8]) = h1;
}

// ================= shared dual-operand K-step (R8 shape) =================
// LDS unit: A 256x32 @0 | B 128x32 @8192 | G 128x32 @12288 (u16 offsets),
// ring of 4 units = 128 KiB. 8 waves 4x2, wave tile 64x64 per operand pair.
// Unit t was published by the SBAR in step t-1. Step t:
//   phase H: read Af/Bf(t) [pre-barrier, unit published] + gload A(t+3)
//            -> sched_barrier -> SBAR -> 16 h-MFMA
//   phase G: read Gf(t) + gload B,G(t+3) -> sched_barrier
//            -> vmcnt(8) [12 outstanding; retires exactly unit t+1's quad]
//            -> SBAR [publishes unit t+1] -> 16 g-MFMA
// Pre-barrier reads overlap laggard waves' previous MFMA cluster (barrier
// skew) -> LDS port stays fed during MFMA. Overwrite of unit t-1 by the
// gloads is safe: every wave's reads of t-1 completed (forced by consuming
// MFMA lgkm waits) before it passed step t-1's publish SBAR.

template<bool PF, int VM>
__device__ __forceinline__ void duo_step(int tt, u16 (*sm)[16384],
    const u16* asrc, const u16* bsrc, const u16* gsrc, size_t a16str,
    int adst0, int adst1, int bdst, int gdst,
    int aoff, int boff, int goff,
    f32x4 (&acch)[4][4], f32x4 (&accg)[4][4])
{
    const u16* sb = &sm[tt & 3][0];
    u16* db = &sm[(tt + 3) & 3][0];
    bf16x8 Af[4], Bf[4], Gf[4];
    // ---- phase H ----
#pragma unroll
    for (int i = 0; i < 4; ++i) Af[i] = *(const bf16x8*)(sb + aoff + i * 512);
#pragma unroll
    for (int i = 0; i < 4; ++i) Bf[i] = *(const bf16x8*)(sb + boff + i * 512);
    if (PF) {
        gload16(asrc + (size_t)(tt + 3) * 32, db + adst0);
        gload16(asrc + (size_t)(tt + 3) * 32 + a16str, db + adst1);
    }
    SB0();   // pin reads/gloads before the barrier
    SBAR();
    __builtin_amdgcn_s_setprio(1);
#pragma unroll
    for (int mi = 0; mi < 4; ++mi)
#pragma unroll
        for (int ni = 0; ni < 4; ++ni)
            acch[mi][ni] = __builtin_amdgcn_mfma_f32_16x16x32_bf16(Af[mi], Bf[ni], acch[mi][ni], 0, 0, 0);
    __builtin_amdgcn_s_setprio(0);
    // ---- phase G ----
#pragma unroll
    for (int i = 0; i < 4; ++i) Gf[i] = *(const bf16x8*)(sb + goff + i * 512);
    if (PF) {
        gload16(bsrc + (size_t)(tt + 3) * 32, db + bdst);
        gload16(gsrc + (size_t)(tt + 3) * 32, db + gdst);
    }
    SB0();
    if (VM == 8)      asm volatile("s_waitcnt vmcnt(8)" ::: "memory");
    else if (VM == 4) asm volatile("s_waitcnt vmcnt(4)" ::: "memory");
    else if (VM == 0) asm volatile("s_waitcnt vmcnt(0)" ::: "memory");
    if (VM >= 0) SBAR();   // publish unit t+1
    __builtin_amdgcn_s_setprio(1);
#pragma unroll
    for (int mi = 0; mi < 4; ++mi)
#pragma unroll
        for (int ni = 0; ni < 4; ++ni)
            accg[mi][ni] = __builtin_amdgcn_mfma_f32_16x16x32_bf16(Af[mi], Gf[ni], accg[mi][ni], 0, 0, 0);
    __builtin_amdgcn_s_setprio(0);
}

// ================= fc_gate: act = silu((x@wfc+bfc)*(x@wg+bg)) =================
__global__ __launch_bounds__(512, 2) void gemm_fc_gate(
    const u16* __restrict__ xh, const u16* __restrict__ fh, const u16* __restrict__ gh,
    const float* __restrict__ bfc, const float* __restrict__ bgt,
    u16* __restrict__ act)
{
    __shared__ __align__(16) u16 sm[4][16384];   // 128 KiB
    const int z  = blockIdx.z;
    // T1: bijective XCD swizzle (256 blocks/expert) -> 4 B/G panels per XCD L2
    const int lin = blockIdx.x + (blockIdx.y << 3);          // gridDim.x == 8
    const int swz = ((lin & 7) << 5) + (lin >> 3);
    const int m0 = (swz & 7) * 256;
    const int n0 = (swz >> 3) * 128;
    const int tid = threadIdx.x;
    const int lane = tid & 63;
    const int wid = tid >> 6;
    const int wr = wid >> 1;     // 0..3
    const int wc = wid & 1;      // 0..1

    // T2 write side: physical chunk (lane&3) of row (lane>>2) carries logical
    // chunk (lane&3) ^ ((row>>1)&3)
    const int cs = ((lane & 3) ^ ((lane >> 3) & 3)) * 8;
    const u16* asrc = xh + ((size_t)z * T_ + m0 + wid * 32 + (lane >> 2)) * D_ + cs;
    const u16* bsrc = fh + ((size_t)z * H_ + n0 + wid * 16 + (lane >> 2)) * D_ + cs;
    const u16* gsrc = gh + ((size_t)z * H_ + n0 + wid * 16 + (lane >> 2)) * D_ + cs;
    const int adst0 = wid * 1024;
    const int adst1 = adst0 + 512;
    const int bdst  = 8192 + wid * 512;
    const int gdst  = 12288 + wid * 512;

    // T2 read side
    const int cswz = (((lane & 15) >> 1) & 3);
    const int aoff = (wr * 64 + (lane & 15)) * 32 + ((lane >> 4) ^ cswz) * 8;
    const int boff = 8192 + (wc * 64 + (lane & 15)) * 32 + ((lane >> 4) ^ cswz) * 8;
    const int goff = boff + 4096;

    f32x4 acch[4][4], accg[4][4];
#pragma unroll
    for (int i = 0; i < 4; ++i)
#pragma unroll
        for (int j = 0; j < 4; ++j) {
            acch[i][j] = (f32x4){0.f, 0.f, 0.f, 0.f};
            accg[i][j] = (f32x4){0.f, 0.f, 0.f, 0.f};
        }

    // prologue: stage units 0,1,2 (A,A,B,G per unit)
#pragma unroll
    for (int u = 0; u < 3; ++u) {
        u16* db = &sm[u][0];
        gload16(asrc + u * 32, db + adst0);
        gload16(asrc + u * 32 + (size_t)16 * D_, db + adst1);
        gload16(bsrc + u * 32, db + bdst);
        gload16(gsrc + u * 32, db + gdst);
    }
    asm volatile("s_waitcnt vmcnt(8)" ::: "memory");   // unit 0 landed (this wave)
    SBAR();                                            // unit 0 published

    const size_t a16 = (size_t)16 * D_;
#pragma unroll 2
    for (int t = 0; t < 28; ++t)
        duo_step<true, 8>(t, sm, asrc, bsrc, gsrc, a16, adst0, adst1, bdst, gdst,
                          aoff, boff, goff, acch, accg);
    duo_step<true,  8>(28, sm, asrc, bsrc, gsrc, a16, adst0, adst1, bdst, gdst,
                       aoff, boff, goff, acch, accg);
    duo_step<false, 4>(29, sm, asrc, bsrc, gsrc, a16, adst0, adst1, bdst, gdst,
                       aoff, boff, goff, acch, accg);
    duo_step<false, 0>(30, sm, asrc, bsrc, gsrc, a16, adst0, adst1, bdst, gdst,
                       aoff, boff, goff, acch, accg);
    duo_step<false, -1>(31, sm, asrc, bsrc, gsrc, a16, adst0, adst1, bdst, gdst,
                       aoff, boff, goff, acch, accg);

    // epilogue: silu(h*g) -> bf16
#pragma unroll
    for (int mi = 0; mi < 4; ++mi) {
#pragma unroll
        for (int ni = 0; ni < 4; ++ni) {
            const int col = n0 + wc * 64 + ni * 16 + (lane & 15);
            const float bh = bfc[(size_t)z * H_ + col];
            const float bg = bgt[(size_t)z * H_ + col];
#pragma unroll
            for (int r = 0; r < 4; ++r) {
                const int row = m0 + wr * 64 + mi * 16 + (lane >> 4) * 4 + r;
                float h = acch[mi][ni][r] + bh;
                float g = accg[mi][ni][r] + bg;
                float zz = h * g;
                float s = zz * __builtin_amdgcn_rcpf(1.0f + __expf(-zz));
                act[((size_t)z * T_ + row) * H_ + col] = (u16)bf16_rne(s);
            }
        }
    }
}

// ================= proj: out = act @ wp + bp =================
// Same dual-operand structure: BN=256 as two 128-col halves of wp (B and G).
__global__ __launch_bounds__(512, 2) void gemm_proj(
    const u16* __restrict__ act, const u16* __restrict__ ph,
    const float* __restrict__ bp, float* __restrict__ out)
{
    __shared__ __align__(16) u16 sm[4][16384];   // 128 KiB
    const int z  = blockIdx.z;
    // 32 tiles/expert: bm = lin&7 (one A-panel per XCD, 2 MB L2-resident), bn = lin>>3
    const int lin = blockIdx.x;                  // gridDim.x == 32
    const int m0 = (lin & 7) * 256;
    const int n0 = (lin >> 3) * 256;
    const int tid = threadIdx.x;
    const int lane = tid & 63;
    const int wid = tid >> 6;
    const int wr = wid >> 1;
    const int wc = wid & 1;

    const int cs = ((lane & 3) ^ ((lane >> 3) & 3)) * 8;
    const u16* asrc = act + ((size_t)z * T_ + m0 + wid * 32 + (lane >> 2)) * H_ + cs;
    const u16* bsrc = ph  + ((size_t)z * D_ + n0 + wid * 16 + (lane >> 2)) * H_ + cs;
    const u16* gsrc = ph  + ((size_t)z * D_ + n0 + 128 + wid * 16 + (lane >> 2)) * H_ + cs;
    const int adst0 = wid * 1024;
    const int adst1 = adst0 + 512;
    const int bdst  = 8192 + wid * 512;
    const int gdst  = 12288 + wid * 512;

    const int cswz = (((lane & 15) >> 1) & 3);
    const int aoff = (wr * 64 + (lane & 15)) * 32 + ((lane >> 4) ^ cswz) * 8;
    const int boff = 8192 + (wc * 64 + (lane & 15)) * 32 + ((lane >> 4) ^ cswz) * 8;
    const int goff = boff + 4096;

    f32x4 acch[4][4], accg[4][4];
#pragma unroll
    for (int i = 0; i < 4; ++i)
#pragma unroll
        for (int j = 0; j < 4; ++j) {
            acch[i][j] = (f32x4){0.f, 0.f, 0.f, 0.f};
            accg[i][j] = (f32x4){0.f, 0.f, 0.f, 0.f};
        }

    // prologue: stage units 0,1,2
#pragma unroll
    for (int u = 0; u < 3; ++u) {
        u16* db = &sm[u][0];
        gload16(asrc + u * 32, db + adst0);
        gload16(asrc + u * 32 + (size_t)16 * H_, db + adst1);
        gload16(bsrc + u * 32, db + bdst);
        gload16(gsrc + u * 32, db + gdst);
    }
    asm volatile("s_waitcnt vmcnt(8)" ::: "memory");
    SBAR();

    const size_t a16 = (size_t)16 * H_;
#pragma unroll 2
    for (int t = 0; t < 124; ++t)
        duo_step<true, 8>(t, sm, asrc, bsrc, gsrc, a16, adst0, adst1, bdst, gdst,
                          aoff, boff, goff, acch, accg);
    duo_step<true,  8>(124, sm, asrc, bsrc, gsrc, a16, adst0, adst1, bdst, gdst,
                       aoff, boff, goff, acch, accg);
    duo_step<false, 4>(125, sm, asrc, bsrc, gsrc, a16, adst0, adst1, bdst, gdst,
                       aoff, boff, goff, acch, accg);
    duo_step<false, 0>(126, sm, asrc, bsrc, gsrc, a16, adst0, adst1, bdst, gdst,
                       aoff, boff, goff, acch, accg);
    duo_step<false, -1>(127, sm, asrc, bsrc, gsrc, a16, adst0, adst1, bdst, gdst,
                       aoff, boff, goff, acch, accg);

    // epilogue: two fp32 column-halves + bias
#pragma unroll
    for (int mi = 0; mi < 4; ++mi) {
#pragma unroll
        for (int ni = 0; ni < 4; ++ni) {
            const int colh = n0 + wc * 64 + ni * 16 + (lane & 15);
            const int colg = colh + 128;
            const float bvh = bp[(size_t)z * D_ + colh];
            const float bvg = bp[(size_t)z * D_ + colg];
#pragma unroll
            for (int r = 0; r < 4; ++r) {
                const int row = m0 + wr * 64 + mi * 16 + (lane >> 4) * 4 + r;
                out[((size_t)z * T_ + row) * D_ + colh] = acch[mi][ni][r] + bvh;
                out[((size_t)z * T_ + row) * D_ + colg] = accg[mi][ni][r] + bvg;
            }
        }
    }
}

extern "C" void kernel_launch(void* const* d_in, const int* in_sizes, int n_in,
                              void* d_out, int out_size, void* d_ws, size_t ws_size,
                              hipStream_t stream) {
    const float* x   = (const float*)d_in[0];
    const float* wfc = (const float*)d_in[1];
    const float* bfc = (const float*)d_in[2];
    const float* wg  = (const float*)d_in[3];
    const float* bg  = (const float*)d_in[4];
    const float* wp  = (const float*)d_in[5];
    const float* bp  = (const float*)d_in[6];
    float* out = (float*)d_out;

    // per-expert ws: xh + fh/gh/ph (transposed bf16) + act(bf16) = 44 MB
    const size_t per_e = ((size_t)T_*D_ + 3*(size_t)D_*H_ + (size_t)T_*H_) * 2;
    int EB = (int)(ws_size / per_e);
    if (EB < 1) EB = 1;
    if (EB > NE) EB = NE;

    for (int e0 = 0; e0 < NE; e0 += EB) {
        const int eb = (NE - e0 < EB) ? (NE - e0) : EB;
        char* p = (char*)d_ws;
        u16* xh = (u16*)p; p += (size_t)eb*T_*D_*2;
        u16* fh = (u16*)p; p += (size_t)eb*D_*H_*2;
        u16* gh = (u16*)p; p += (size_t)eb*D_*H_*2;
        u16* ph = (u16*)p; p += (size_t)eb*H_*D_*2;
        u16* act = (u16*)p;

        const int n4 = eb * T_ * D_ / 4;
        tobf16_kernel<<<dim3((n4 + 255) / 256), 256, 0, stream>>>(
            x + (size_t)e0*T_*D_, xh, n4);
        transpose_hi_kernel<<<dim3(D_/64, H_/64, eb), 256, 0, stream>>>(
            wfc + (size_t)e0*D_*H_, fh, D_, H_);
        transpose_hi_kernel<<<dim3(D_/64, H_/64, eb), 256, 0, stream>>>(
            wg + (size_t)e0*D_*H_, gh, D_, H_);
        transpose_hi_kernel<<<dim3(H_/64, D_/64, eb), 256, 0, stream>>>(
            wp + (size_t)e0*H_*D_, ph, H_, D_);
        gemm_fc_gate<<<dim3(8, 32, eb), 512, 0, stream>>>(
            xh, fh, gh, bfc + (size_t)e0*H_, bg + (size_t)e0*H_, act);
        gemm_proj<<<dim3(32, 1, eb), 512, 0, stream>>>(
            act, ph, bp + (size_t)e0*D_, out + (size_t)e0*T_*D_);
    }
}